// Round 1
// baseline (1814.303 us; speedup 1.0000x reference)
//
#include <hip/hip_runtime.h>
#include <cstdint>
#include <cstddef>

typedef unsigned short u16;
typedef __bf16 bf16x8 __attribute__((ext_vector_type(8)));
typedef unsigned short u16x8 __attribute__((ext_vector_type(8)));
typedef unsigned short u16x4 __attribute__((ext_vector_type(4)));
typedef float f32x4 __attribute__((ext_vector_type(4)));

#define NB   16
#define TQ   2048
#define TV   2048
#define DDEC 1024   // decoder dim (query / keys inner)
#define DENC 512    // encoder dim (value inner)
#define CTXW (DENC + DDEC)  // 1536

#define LSTR 40     // LDS row stride in u16: 32 data + 8 pad (80 B, 16B-aligned)

static __device__ __forceinline__ u16 f2bf(float f) {
    unsigned u = __builtin_bit_cast(unsigned, f);
    return (u16)((u + 0x7fffu + ((u >> 16) & 1u)) >> 16);  // RNE
}
static __device__ __forceinline__ float bf2f(u16 h) {
    return __builtin_bit_cast(float, ((unsigned)h) << 16);
}

// ---------------- transpose+split W [DENC,DDEC] -> Wt hi/lo [DDEC,DENC] ------
__global__ __launch_bounds__(256)
void lk_prep_wt(const float* __restrict__ W, u16* __restrict__ Wh, u16* __restrict__ Wl)
{
    __shared__ float ts[32][36];
    const int t = threadIdx.x;
    const int r = t >> 3, c = (t & 7) * 4;
    const int d0 = blockIdx.x * 32, e0 = blockIdx.y * 32;
    *(float4*)&ts[r][c] = *(const float4*)(W + (size_t)(e0 + r) * DDEC + d0 + c);
    __syncthreads();
    u16x4 hv, lv;
    #pragma unroll
    for (int x = 0; x < 4; ++x) {
        const float f = ts[c + x][r];
        const u16 h = f2bf(f);
        hv[x] = h; lv[x] = f2bf(f - bf2f(h));
    }
    *(u16x4*)(Wh + (size_t)(d0 + r) * DENC + e0 + c) = hv;
    *(u16x4*)(Wl + (size_t)(d0 + r) * DENC + e0 + c) = lv;
}

// ---------------- transpose value [NB,TV,DENC] -> Vt bf16 [NB,DENC,TV] -------
__global__ __launch_bounds__(256)
void lk_prep_vt(const float* __restrict__ V, u16* __restrict__ Vt)
{
    __shared__ float ts[32][36];
    const int t = threadIdx.x;
    const int r = t >> 3, c = (t & 7) * 4;
    const int e0 = blockIdx.x * 32, v0 = blockIdx.y * 32;
    const size_t bin  = (size_t)blockIdx.z * TV * DENC;
    const size_t bout = (size_t)blockIdx.z * DENC * TV;
    *(float4*)&ts[r][c] = *(const float4*)(V + bin + (size_t)(v0 + r) * DENC + e0 + c);
    __syncthreads();
    u16x4 hv;
    #pragma unroll
    for (int x = 0; x < 4; ++x) hv[x] = f2bf(ts[c + x][r]);
    *(u16x4*)(Vt + bout + (size_t)(e0 + r) * TV + v0 + c) = hv;
}

// ------- GEMM1: keys = value @ W + b (bf16x3), epilogue splits to hi/lo ------
// M = NB*TV (flattened), N = DDEC, K = DENC. NT form: B' = W^T rows.
__global__ __launch_bounds__(256)
void lk_gemm_keys(const float* __restrict__ A, const u16* __restrict__ Bh,
                  const u16* __restrict__ Bl, const float* __restrict__ bias,
                  u16* __restrict__ Chi, u16* __restrict__ Clo)
{
    __shared__ u16 lAh[128*LSTR], lAl[128*LSTR], lBh[128*LSTR], lBl[128*LSTR];
    const int m0 = blockIdx.x * 128, n0 = blockIdx.y * 128;
    const int t = threadIdx.x;
    const int w = t >> 6, lane = t & 63, l15 = lane & 15, quad = lane >> 4;

    f32x4 acc[2][8];
    #pragma unroll
    for (int i = 0; i < 2; ++i)
        #pragma unroll
        for (int j = 0; j < 8; ++j) acc[i][j] = (f32x4){0.f,0.f,0.f,0.f};

    const int ar = t >> 3, ac = (t & 7) * 4;
    const int br = t >> 2, bc = (t & 3) * 8;

    for (int k0 = 0; k0 < DENC; k0 += 32) {
        #pragma unroll
        for (int it = 0; it < 4; ++it) {
            const int r = ar + it * 32;
            const float4 v = *(const float4*)(A + (size_t)(m0 + r) * DENC + k0 + ac);
            const u16 h0=f2bf(v.x), h1=f2bf(v.y), h2=f2bf(v.z), h3=f2bf(v.w);
            u16x4 hv = {h0,h1,h2,h3};
            u16x4 lv = {f2bf(v.x-bf2f(h0)), f2bf(v.y-bf2f(h1)),
                        f2bf(v.z-bf2f(h2)), f2bf(v.w-bf2f(h3))};
            *(u16x4*)&lAh[r*LSTR+ac] = hv;
            *(u16x4*)&lAl[r*LSTR+ac] = lv;
        }
        #pragma unroll
        for (int it = 0; it < 2; ++it) {
            const int r = br + it * 64;
            *(u16x8*)&lBh[r*LSTR+bc] = *(const u16x8*)(Bh + (size_t)(n0 + r) * DENC + k0 + bc);
            *(u16x8*)&lBl[r*LSTR+bc] = *(const u16x8*)(Bl + (size_t)(n0 + r) * DENC + k0 + bc);
        }
        __syncthreads();
        bf16x8 ah[2], al[2];
        #pragma unroll
        for (int tm = 0; tm < 2; ++tm) {
            const int row = w*32 + tm*16 + l15;
            ah[tm] = __builtin_bit_cast(bf16x8, *(const u16x8*)&lAh[row*LSTR + quad*8]);
            al[tm] = __builtin_bit_cast(bf16x8, *(const u16x8*)&lAl[row*LSTR + quad*8]);
        }
        #pragma unroll
        for (int tn = 0; tn < 8; ++tn) {
            const int col = tn*16 + l15;
            const bf16x8 bh = __builtin_bit_cast(bf16x8, *(const u16x8*)&lBh[col*LSTR + quad*8]);
            const bf16x8 bl = __builtin_bit_cast(bf16x8, *(const u16x8*)&lBl[col*LSTR + quad*8]);
            #pragma unroll
            for (int tm = 0; tm < 2; ++tm) {
                acc[tm][tn] = __builtin_amdgcn_mfma_f32_16x16x32_bf16(ah[tm], bh, acc[tm][tn], 0,0,0);
                acc[tm][tn] = __builtin_amdgcn_mfma_f32_16x16x32_bf16(ah[tm], bl, acc[tm][tn], 0,0,0);
                acc[tm][tn] = __builtin_amdgcn_mfma_f32_16x16x32_bf16(al[tm], bh, acc[tm][tn], 0,0,0);
            }
        }
        __syncthreads();
    }
    #pragma unroll
    for (int tn = 0; tn < 8; ++tn) {
        const int col = n0 + tn*16 + l15;
        const float bv = bias[col];
        #pragma unroll
        for (int tm = 0; tm < 2; ++tm)
            #pragma unroll
            for (int r = 0; r < 4; ++r) {
                const int row = m0 + w*32 + tm*16 + quad*4 + r;
                const float c = acc[tm][tn][r] + bv;
                const u16 h = f2bf(c);
                Chi[(size_t)row*DDEC + col] = h;
                Clo[(size_t)row*DDEC + col] = f2bf(c - bf2f(h));
            }
    }
}

// ------- GEMM2: scores[b,q,v] = Q[b] @ keys[b]^T (bf16x3), fp32 out ----------
__global__ __launch_bounds__(256)
void lk_gemm_scores(const float* __restrict__ Q, const u16* __restrict__ Khi,
                    const u16* __restrict__ Klo, float* __restrict__ Sc)
{
    __shared__ u16 lAh[128*LSTR], lAl[128*LSTR], lBh[128*LSTR], lBl[128*LSTR];
    const int b = blockIdx.z;
    const int m0 = blockIdx.x * 128, n0 = blockIdx.y * 128;
    const int t = threadIdx.x;
    const int w = t >> 6, lane = t & 63, l15 = lane & 15, quad = lane >> 4;

    const float* Ab = Q + (size_t)b * TQ * DDEC;
    const u16* Bh = Khi + (size_t)b * TV * DDEC;
    const u16* Bl = Klo + (size_t)b * TV * DDEC;

    f32x4 acc[2][8];
    #pragma unroll
    for (int i = 0; i < 2; ++i)
        #pragma unroll
        for (int j = 0; j < 8; ++j) acc[i][j] = (f32x4){0.f,0.f,0.f,0.f};

    const int ar = t >> 3, ac = (t & 7) * 4;
    const int br = t >> 2, bc = (t & 3) * 8;

    for (int k0 = 0; k0 < DDEC; k0 += 32) {
        #pragma unroll
        for (int it = 0; it < 4; ++it) {
            const int r = ar + it * 32;
            const float4 v = *(const float4*)(Ab + (size_t)(m0 + r) * DDEC + k0 + ac);
            const u16 h0=f2bf(v.x), h1=f2bf(v.y), h2=f2bf(v.z), h3=f2bf(v.w);
            u16x4 hv = {h0,h1,h2,h3};
            u16x4 lv = {f2bf(v.x-bf2f(h0)), f2bf(v.y-bf2f(h1)),
                        f2bf(v.z-bf2f(h2)), f2bf(v.w-bf2f(h3))};
            *(u16x4*)&lAh[r*LSTR+ac] = hv;
            *(u16x4*)&lAl[r*LSTR+ac] = lv;
        }
        #pragma unroll
        for (int it = 0; it < 2; ++it) {
            const int r = br + it * 64;
            *(u16x8*)&lBh[r*LSTR+bc] = *(const u16x8*)(Bh + (size_t)(n0 + r) * DDEC + k0 + bc);
            *(u16x8*)&lBl[r*LSTR+bc] = *(const u16x8*)(Bl + (size_t)(n0 + r) * DDEC + k0 + bc);
        }
        __syncthreads();
        bf16x8 ah[2], al[2];
        #pragma unroll
        for (int tm = 0; tm < 2; ++tm) {
            const int row = w*32 + tm*16 + l15;
            ah[tm] = __builtin_bit_cast(bf16x8, *(const u16x8*)&lAh[row*LSTR + quad*8]);
            al[tm] = __builtin_bit_cast(bf16x8, *(const u16x8*)&lAl[row*LSTR + quad*8]);
        }
        #pragma unroll
        for (int tn = 0; tn < 8; ++tn) {
            const int col = tn*16 + l15;
            const bf16x8 bh = __builtin_bit_cast(bf16x8, *(const u16x8*)&lBh[col*LSTR + quad*8]);
            const bf16x8 bl = __builtin_bit_cast(bf16x8, *(const u16x8*)&lBl[col*LSTR + quad*8]);
            #pragma unroll
            for (int tm = 0; tm < 2; ++tm) {
                acc[tm][tn] = __builtin_amdgcn_mfma_f32_16x16x32_bf16(ah[tm], bh, acc[tm][tn], 0,0,0);
                acc[tm][tn] = __builtin_amdgcn_mfma_f32_16x16x32_bf16(ah[tm], bl, acc[tm][tn], 0,0,0);
                acc[tm][tn] = __builtin_amdgcn_mfma_f32_16x16x32_bf16(al[tm], bh, acc[tm][tn], 0,0,0);
            }
        }
        __syncthreads();
    }
    float* Sb = Sc + (size_t)b * TQ * TV;
    #pragma unroll
    for (int tm = 0; tm < 2; ++tm)
        #pragma unroll
        for (int tn = 0; tn < 8; ++tn) {
            const int col = n0 + tn*16 + l15;
            #pragma unroll
            for (int r = 0; r < 4; ++r) {
                const int row = m0 + w*32 + tm*16 + quad*4 + r;
                Sb[(size_t)row*TV + col] = acc[tm][tn][r];
            }
        }
}

// ---------------- softmax rows in place: [NB*TQ, TV] -------------------------
__global__ __launch_bounds__(256)
void lk_softmax(float* __restrict__ S)
{
    float* p = S + (size_t)blockIdx.x * TV;
    const int t = threadIdx.x;
    const float4 v0 = *(const float4*)(p + 4*t);
    const float4 v1 = *(const float4*)(p + 1024 + 4*t);
    float mx = fmaxf(fmaxf(fmaxf(v0.x, v0.y), fmaxf(v0.z, v0.w)),
                     fmaxf(fmaxf(v1.x, v1.y), fmaxf(v1.z, v1.w)));
    #pragma unroll
    for (int off = 32; off > 0; off >>= 1) mx = fmaxf(mx, __shfl_xor(mx, off, 64));
    __shared__ float sred[4];
    const int w = t >> 6;
    if ((t & 63) == 0) sred[w] = mx;
    __syncthreads();
    mx = fmaxf(fmaxf(sred[0], sred[1]), fmaxf(sred[2], sred[3]));
    __syncthreads();
    float e[8];
    e[0]=__expf(v0.x-mx); e[1]=__expf(v0.y-mx); e[2]=__expf(v0.z-mx); e[3]=__expf(v0.w-mx);
    e[4]=__expf(v1.x-mx); e[5]=__expf(v1.y-mx); e[6]=__expf(v1.z-mx); e[7]=__expf(v1.w-mx);
    float s = ((e[0]+e[1])+(e[2]+e[3])) + ((e[4]+e[5])+(e[6]+e[7]));
    #pragma unroll
    for (int off = 32; off > 0; off >>= 1) s += __shfl_xor(s, off, 64);
    if ((t & 63) == 0) sred[w] = s;
    __syncthreads();
    s = (sred[0]+sred[1]) + (sred[2]+sred[3]);
    const float inv = 1.0f / s;
    float4 o0 = {e[0]*inv, e[1]*inv, e[2]*inv, e[3]*inv};
    float4 o1 = {e[4]*inv, e[5]*inv, e[6]*inv, e[7]*inv};
    *(float4*)(p + 4*t) = o0;
    *(float4*)(p + 1024 + 4*t) = o1;
}

// ------- GEMM3: context = align @ value  (single bf16; NT via Vt) ------------
// M=TQ, N=DENC, K=TV per batch. Output written to ctx cols [0, DENC).
__global__ __launch_bounds__(256)
void lk_gemm_ctx(const float* __restrict__ P, const u16* __restrict__ Vt,
                 float* __restrict__ C)
{
    __shared__ u16 lA[128*LSTR], lB[128*LSTR];
    const int b = blockIdx.z;
    const int m0 = blockIdx.x * 128, n0 = blockIdx.y * 128;
    const int t = threadIdx.x;
    const int w = t >> 6, lane = t & 63, l15 = lane & 15, quad = lane >> 4;

    const float* Pb = P + (size_t)b * TQ * TV;
    const u16* Bb = Vt + (size_t)b * DENC * TV;

    f32x4 acc[2][8];
    #pragma unroll
    for (int i = 0; i < 2; ++i)
        #pragma unroll
        for (int j = 0; j < 8; ++j) acc[i][j] = (f32x4){0.f,0.f,0.f,0.f};

    const int ar = t >> 3, ac = (t & 7) * 4;
    const int br = t >> 2, bc = (t & 3) * 8;

    for (int k0 = 0; k0 < TV; k0 += 32) {
        #pragma unroll
        for (int it = 0; it < 4; ++it) {
            const int r = ar + it * 32;
            const float4 v = *(const float4*)(Pb + (size_t)(m0 + r) * TV + k0 + ac);
            u16x4 hv = {f2bf(v.x), f2bf(v.y), f2bf(v.z), f2bf(v.w)};
            *(u16x4*)&lA[r*LSTR+ac] = hv;
        }
        #pragma unroll
        for (int it = 0; it < 2; ++it) {
            const int r = br + it * 64;
            *(u16x8*)&lB[r*LSTR+bc] = *(const u16x8*)(Bb + (size_t)(n0 + r) * TV + k0 + bc);
        }
        __syncthreads();
        bf16x8 af[2];
        #pragma unroll
        for (int tm = 0; tm < 2; ++tm) {
            const int row = w*32 + tm*16 + l15;
            af[tm] = __builtin_bit_cast(bf16x8, *(const u16x8*)&lA[row*LSTR + quad*8]);
        }
        #pragma unroll
        for (int tn = 0; tn < 8; ++tn) {
            const int col = tn*16 + l15;
            const bf16x8 bf = __builtin_bit_cast(bf16x8, *(const u16x8*)&lB[col*LSTR + quad*8]);
            #pragma unroll
            for (int tm = 0; tm < 2; ++tm)
                acc[tm][tn] = __builtin_amdgcn_mfma_f32_16x16x32_bf16(af[tm], bf, acc[tm][tn], 0,0,0);
        }
        __syncthreads();
    }
    float* Cb = C + (size_t)b * TQ * CTXW;
    #pragma unroll
    for (int tm = 0; tm < 2; ++tm)
        #pragma unroll
        for (int tn = 0; tn < 8; ++tn) {
            const int col = n0 + tn*16 + l15;
            #pragma unroll
            for (int r = 0; r < 4; ++r) {
                const int row = m0 + w*32 + tm*16 + quad*4 + r;
                Cb[(size_t)row*CTXW + col] = acc[tm][tn][r];
            }
        }
}

// ---------------- copy query into ctx cols [DENC, DENC+DDEC) -----------------
__global__ __launch_bounds__(256)
void lk_copy_q(const float* __restrict__ Q, float* __restrict__ C)
{
    const size_t idx = (size_t)blockIdx.x * 256 + threadIdx.x;   // float4 index
    const int d4 = (int)(idx & 255);       // DDEC/4 = 256
    const size_t row = idx >> 8;           // b*TQ + q
    const float4 v = *(const float4*)(Q + (row << 10) + 4*d4);
    *(float4*)(C + row * CTXW + DENC + 4*d4) = v;
}

// ---------------- in-place square transpose per batch: [TQ,TV] --------------
__global__ __launch_bounds__(256)
void lk_transpose(float* __restrict__ A)
{
    const int i = blockIdx.x, j = blockIdx.y;
    if (j < i) return;
    float* Ab = A + (size_t)blockIdx.z * TQ * TV;
    __shared__ float ta[32][36], tb[32][36];
    const int t = threadIdx.x;
    const int r = t >> 3, c = (t & 7) * 4;
    float* pij = Ab + (size_t)(i*32) * TV + j*32;
    float* pji = Ab + (size_t)(j*32) * TV + i*32;
    const float4 va = *(const float4*)(pij + (size_t)r * TV + c);
    *(float4*)&ta[r][c] = va;
    if (i != j) {
        const float4 vb = *(const float4*)(pji + (size_t)r * TV + c);
        *(float4*)&tb[r][c] = vb;
    }
    __syncthreads();
    float4 oa = { ta[c+0][r], ta[c+1][r], ta[c+2][r], ta[c+3][r] };
    *(float4*)(pji + (size_t)r * TV + c) = oa;
    if (i != j) {
        float4 ob = { tb[c+0][r], tb[c+1][r], tb[c+2][r], tb[c+3][r] };
        *(float4*)(pij + (size_t)r * TV + c) = ob;
    }
}

extern "C" void kernel_launch(void* const* d_in, const int* in_sizes, int n_in,
                              void* d_out, int out_size, void* d_ws, size_t ws_size,
                              hipStream_t stream)
{
    (void)in_sizes; (void)n_in; (void)out_size; (void)ws_size;
    const float* Q    = (const float*)d_in[0];
    const float* V    = (const float*)d_in[1];
    const float* W    = (const float*)d_in[2];
    const float* bias = (const float*)d_in[3];
    float* out = (float*)d_out;

    float* ctx   = out;                                   // [NB, TQ, CTXW]
    float* align = out + (size_t)NB * TQ * CTXW;          // [NB, TQ, TV]

    // keys (bf16 hi/lo) staged in the ctx region (134 MB < 201 MB);
    // consumed by gemm_scores before gemm_ctx/copy_q overwrite it.
    u16* k_hi = (u16*)ctx;
    u16* k_lo = k_hi + (size_t)NB * TV * DDEC;

    // ws: Wt hi/lo (2 MB) + Vt (32 MB) = 34.6 MB
    u16* wt_hi = (u16*)d_ws;
    u16* wt_lo = wt_hi + (size_t)DDEC * DENC;
    u16* v_t   = wt_lo + (size_t)DDEC * DENC;             // [NB, DENC, TV]

    lk_prep_wt<<<dim3(DDEC/32, DENC/32), 256, 0, stream>>>(W, wt_hi, wt_lo);
    lk_prep_vt<<<dim3(DENC/32, TV/32, NB), 256, 0, stream>>>(V, v_t);
    lk_gemm_keys<<<dim3(NB*TV/128, DDEC/128), 256, 0, stream>>>(V, wt_hi, wt_lo, bias, k_hi, k_lo);
    lk_gemm_scores<<<dim3(TQ/128, TV/128, NB), 256, 0, stream>>>(Q, k_hi, k_lo, align);
    lk_softmax<<<NB*TQ, 256, 0, stream>>>(align);
    lk_gemm_ctx<<<dim3(TQ/128, DENC/128, NB), 256, 0, stream>>>(align, v_t, ctx);
    lk_copy_q<<<NB*TQ*DDEC/1024, 256, 0, stream>>>(Q, ctx);
    lk_transpose<<<dim3(TV/32, TV/32, NB), 256, 0, stream>>>(align);
}

// Round 2
// 1483.952 us; speedup vs baseline: 1.2226x; 1.2226x over previous
//
#include <hip/hip_runtime.h>
#include <cstdint>
#include <cstddef>

typedef unsigned short u16;
typedef __bf16 bf16x8 __attribute__((ext_vector_type(8)));
typedef unsigned short u16x8 __attribute__((ext_vector_type(8)));
typedef unsigned short u16x4 __attribute__((ext_vector_type(4)));
typedef float f32x4 __attribute__((ext_vector_type(4)));

#define NB   16
#define TQ   2048
#define TV   2048
#define DDEC 1024   // decoder dim (query inner)
#define DENC 512    // encoder dim (value inner / Q' width)
#define CTXW (DENC + DDEC)  // 1536

#define ASTR 40     // padded LDS row stride (u16) for VALU-written A tiles

static __device__ __forceinline__ u16 f2bf(float f) {
    unsigned u = __builtin_bit_cast(unsigned, f);
    return (u16)((u + 0x7fffu + ((u >> 16) & 1u)) >> 16);  // RNE
}
static __device__ __forceinline__ float bf2f(u16 h) {
    return __builtin_bit_cast(float, ((unsigned)h) << 16);
}

// Stage one [128][32]-u16 tile (unpadded, 8 KB) global -> LDS via
// global_load_lds width=16. LDS base per chunk is wave-uniform; HW scatters
// lane i to base + i*16 (m97 structure).
static __device__ __forceinline__ void stage_tile(
    u16* __restrict__ lds_tile, const u16* __restrict__ gsrc,
    int ldb, int w, int lane)
{
    #pragma unroll
    for (int p = 0; p < 2; ++p) {
        const int ci  = p * 4 + w;               // chunk 0..7 (1024 B each)
        const int row = ci * 16 + (lane >> 2);
        const int col = (lane & 3) * 8;
        const u16* g = gsrc + (size_t)row * ldb + col;
        u16* l = lds_tile + ci * 512;            // wave-uniform chunk base
        __builtin_amdgcn_global_load_lds(
            (const __attribute__((address_space(1))) void*)g,
            (__attribute__((address_space(3))) void*)l, 16, 0, 0);
    }
}

// ---------------- split W [DENC,DDEC] -> Wh/Wl (same layout) -----------------
__global__ __launch_bounds__(256)
void lk_prep_w(const float* __restrict__ W, u16* __restrict__ Wh, u16* __restrict__ Wl)
{
    const size_t i = ((size_t)blockIdx.x * 256 + threadIdx.x) * 4;
    const float4 v = *(const float4*)(W + i);
    const u16 h0=f2bf(v.x), h1=f2bf(v.y), h2=f2bf(v.z), h3=f2bf(v.w);
    u16x4 hv = {h0,h1,h2,h3};
    u16x4 lv = {f2bf(v.x-bf2f(h0)), f2bf(v.y-bf2f(h1)),
                f2bf(v.z-bf2f(h2)), f2bf(v.w-bf2f(h3))};
    *(u16x4*)(Wh + i) = hv;
    *(u16x4*)(Wl + i) = lv;
}

// -------- split V [NB,TV,DENC] -> Vh/Vl (same layout) + Vt hi [NB,DENC,TV] ---
__global__ __launch_bounds__(256)
void lk_prep_v(const float* __restrict__ V, u16* __restrict__ Vh,
               u16* __restrict__ Vl, u16* __restrict__ Vt)
{
    __shared__ float ts[32][36];
    const int t = threadIdx.x;
    const int r = t >> 3, c = (t & 7) * 4;
    const int e0 = blockIdx.x * 32, v0 = blockIdx.y * 32;
    const size_t bin  = (size_t)blockIdx.z * TV * DENC;
    const float4 v = *(const float4*)(V + bin + (size_t)(v0 + r) * DENC + e0 + c);
    *(float4*)&ts[r][c] = v;
    const u16 h0=f2bf(v.x), h1=f2bf(v.y), h2=f2bf(v.z), h3=f2bf(v.w);
    u16x4 hv = {h0,h1,h2,h3};
    u16x4 lv = {f2bf(v.x-bf2f(h0)), f2bf(v.y-bf2f(h1)),
                f2bf(v.z-bf2f(h2)), f2bf(v.w-bf2f(h3))};
    *(u16x4*)(Vh + bin + (size_t)(v0 + r) * DENC + e0 + c) = hv;
    *(u16x4*)(Vl + bin + (size_t)(v0 + r) * DENC + e0 + c) = lv;
    __syncthreads();
    u16x4 tv;
    #pragma unroll
    for (int x = 0; x < 4; ++x) tv[x] = f2bf(ts[c + x][r]);
    *(u16x4*)(Vt + (size_t)blockIdx.z * DENC * TV + (size_t)(e0 + r) * TV + v0 + c) = tv;
}

// ------- GEMM1: Q' = Q @ W^T (bf16x3). M=NB*TQ, N=DENC, K=DDEC. -------------
// B'[n=e, k=d] = W[e,d] directly (row-major). Epilogue splits Q' -> hi/lo.
__global__ __launch_bounds__(256)
void lk_gemm_qw(const float* __restrict__ A, const u16* __restrict__ Bh,
                const u16* __restrict__ Bl, u16* __restrict__ Chi,
                u16* __restrict__ Clo)
{
    __shared__ u16 lAh[128*ASTR], lAl[128*ASTR], lBh[128*32], lBl[128*32];
    const int m0 = blockIdx.x * 128, n0 = blockIdx.y * 128;
    const int t = threadIdx.x;
    const int w = t >> 6, lane = t & 63, l15 = lane & 15, quad = lane >> 4;

    f32x4 acc[2][8];
    #pragma unroll
    for (int i = 0; i < 2; ++i)
        #pragma unroll
        for (int j = 0; j < 8; ++j) acc[i][j] = (f32x4){0.f,0.f,0.f,0.f};

    const int ar = t >> 3, ac = (t & 7) * 4;

    for (int k0 = 0; k0 < DDEC; k0 += 32) {
        stage_tile(lBh, Bh + (size_t)n0 * DDEC + k0, DDEC, w, lane);
        stage_tile(lBl, Bl + (size_t)n0 * DDEC + k0, DDEC, w, lane);
        #pragma unroll
        for (int it = 0; it < 4; ++it) {
            const int r = ar + it * 32;
            const float4 v = *(const float4*)(A + (size_t)(m0 + r) * DDEC + k0 + ac);
            const u16 h0=f2bf(v.x), h1=f2bf(v.y), h2=f2bf(v.z), h3=f2bf(v.w);
            u16x4 hv = {h0,h1,h2,h3};
            u16x4 lv = {f2bf(v.x-bf2f(h0)), f2bf(v.y-bf2f(h1)),
                        f2bf(v.z-bf2f(h2)), f2bf(v.w-bf2f(h3))};
            *(u16x4*)&lAh[r*ASTR+ac] = hv;
            *(u16x4*)&lAl[r*ASTR+ac] = lv;
        }
        __syncthreads();
        bf16x8 ah[2], al[2];
        #pragma unroll
        for (int tm = 0; tm < 2; ++tm) {
            const int row = w*32 + tm*16 + l15;
            ah[tm] = __builtin_bit_cast(bf16x8, *(const u16x8*)&lAh[row*ASTR + quad*8]);
            al[tm] = __builtin_bit_cast(bf16x8, *(const u16x8*)&lAl[row*ASTR + quad*8]);
        }
        #pragma unroll
        for (int tn = 0; tn < 8; ++tn) {
            const int col = tn*16 + l15;
            const bf16x8 bh = __builtin_bit_cast(bf16x8, *(const u16x8*)&lBh[col*32 + quad*8]);
            const bf16x8 bl = __builtin_bit_cast(bf16x8, *(const u16x8*)&lBl[col*32 + quad*8]);
            #pragma unroll
            for (int tm = 0; tm < 2; ++tm) {
                acc[tm][tn] = __builtin_amdgcn_mfma_f32_16x16x32_bf16(ah[tm], bh, acc[tm][tn], 0,0,0);
                acc[tm][tn] = __builtin_amdgcn_mfma_f32_16x16x32_bf16(ah[tm], bl, acc[tm][tn], 0,0,0);
                acc[tm][tn] = __builtin_amdgcn_mfma_f32_16x16x32_bf16(al[tm], bh, acc[tm][tn], 0,0,0);
            }
        }
        __syncthreads();
    }
    #pragma unroll
    for (int tn = 0; tn < 8; ++tn) {
        const int col = n0 + tn*16 + l15;
        #pragma unroll
        for (int tm = 0; tm < 2; ++tm)
            #pragma unroll
            for (int r = 0; r < 4; ++r) {
                const int row = m0 + w*32 + tm*16 + quad*4 + r;
                const float c = acc[tm][tn][r];
                const u16 h = f2bf(c);
                Chi[(size_t)row*DENC + col] = h;
                Clo[(size_t)row*DENC + col] = f2bf(c - bf2f(h));
            }
    }
}

// ------- GEMM2: scores[b,q,v] = Q'[b] @ V[b]^T (bf16x3), K=DENC=512 ----------
// All four operand tiles staged via global_load_lds (no VALU split in loop).
__global__ __launch_bounds__(256)
void lk_gemm_scores(const u16* __restrict__ Ah_g, const u16* __restrict__ Al_g,
                    const u16* __restrict__ Bh_g, const u16* __restrict__ Bl_g,
                    float* __restrict__ Sc)
{
    __shared__ u16 lAh[128*32], lAl[128*32], lBh[128*32], lBl[128*32];
    const int b = blockIdx.z;
    const int m0 = blockIdx.x * 128, n0 = blockIdx.y * 128;
    const int t = threadIdx.x;
    const int w = t >> 6, lane = t & 63, l15 = lane & 15, quad = lane >> 4;

    const u16* Ab_h = Ah_g + (size_t)b * TQ * DENC + (size_t)m0 * DENC;
    const u16* Ab_l = Al_g + (size_t)b * TQ * DENC + (size_t)m0 * DENC;
    const u16* Bb_h = Bh_g + (size_t)b * TV * DENC + (size_t)n0 * DENC;
    const u16* Bb_l = Bl_g + (size_t)b * TV * DENC + (size_t)n0 * DENC;

    f32x4 acc[2][8];
    #pragma unroll
    for (int i = 0; i < 2; ++i)
        #pragma unroll
        for (int j = 0; j < 8; ++j) acc[i][j] = (f32x4){0.f,0.f,0.f,0.f};

    for (int k0 = 0; k0 < DENC; k0 += 32) {
        stage_tile(lAh, Ab_h + k0, DENC, w, lane);
        stage_tile(lAl, Ab_l + k0, DENC, w, lane);
        stage_tile(lBh, Bb_h + k0, DENC, w, lane);
        stage_tile(lBl, Bb_l + k0, DENC, w, lane);
        __syncthreads();
        bf16x8 ah[2], al[2];
        #pragma unroll
        for (int tm = 0; tm < 2; ++tm) {
            const int row = w*32 + tm*16 + l15;
            ah[tm] = __builtin_bit_cast(bf16x8, *(const u16x8*)&lAh[row*32 + quad*8]);
            al[tm] = __builtin_bit_cast(bf16x8, *(const u16x8*)&lAl[row*32 + quad*8]);
        }
        #pragma unroll
        for (int tn = 0; tn < 8; ++tn) {
            const int col = tn*16 + l15;
            const bf16x8 bh = __builtin_bit_cast(bf16x8, *(const u16x8*)&lBh[col*32 + quad*8]);
            const bf16x8 bl = __builtin_bit_cast(bf16x8, *(const u16x8*)&lBl[col*32 + quad*8]);
            #pragma unroll
            for (int tm = 0; tm < 2; ++tm) {
                acc[tm][tn] = __builtin_amdgcn_mfma_f32_16x16x32_bf16(ah[tm], bh, acc[tm][tn], 0,0,0);
                acc[tm][tn] = __builtin_amdgcn_mfma_f32_16x16x32_bf16(ah[tm], bl, acc[tm][tn], 0,0,0);
                acc[tm][tn] = __builtin_amdgcn_mfma_f32_16x16x32_bf16(al[tm], bh, acc[tm][tn], 0,0,0);
            }
        }
        __syncthreads();
    }
    float* Sb = Sc + (size_t)b * TQ * TV;
    #pragma unroll
    for (int tm = 0; tm < 2; ++tm)
        #pragma unroll
        for (int tn = 0; tn < 8; ++tn) {
            const int col = n0 + tn*16 + l15;
            #pragma unroll
            for (int r = 0; r < 4; ++r) {
                const int row = m0 + w*32 + tm*16 + quad*4 + r;
                Sb[(size_t)row*TV + col] = acc[tm][tn][r];
            }
        }
}

// ---------------- softmax rows in place: [NB*TQ, TV] -------------------------
__global__ __launch_bounds__(256)
void lk_softmax(float* __restrict__ S)
{
    float* p = S + (size_t)blockIdx.x * TV;
    const int t = threadIdx.x;
    const float4 v0 = *(const float4*)(p + 4*t);
    const float4 v1 = *(const float4*)(p + 1024 + 4*t);
    float mx = fmaxf(fmaxf(fmaxf(v0.x, v0.y), fmaxf(v0.z, v0.w)),
                     fmaxf(fmaxf(v1.x, v1.y), fmaxf(v1.z, v1.w)));
    #pragma unroll
    for (int off = 32; off > 0; off >>= 1) mx = fmaxf(mx, __shfl_xor(mx, off, 64));
    __shared__ float sred[4];
    const int w = t >> 6;
    if ((t & 63) == 0) sred[w] = mx;
    __syncthreads();
    mx = fmaxf(fmaxf(sred[0], sred[1]), fmaxf(sred[2], sred[3]));
    __syncthreads();
    float e[8];
    e[0]=__expf(v0.x-mx); e[1]=__expf(v0.y-mx); e[2]=__expf(v0.z-mx); e[3]=__expf(v0.w-mx);
    e[4]=__expf(v1.x-mx); e[5]=__expf(v1.y-mx); e[6]=__expf(v1.z-mx); e[7]=__expf(v1.w-mx);
    float s = ((e[0]+e[1])+(e[2]+e[3])) + ((e[4]+e[5])+(e[6]+e[7]));
    #pragma unroll
    for (int off = 32; off > 0; off >>= 1) s += __shfl_xor(s, off, 64);
    if ((t & 63) == 0) sred[w] = s;
    __syncthreads();
    s = (sred[0]+sred[1]) + (sred[2]+sred[3]);
    const float inv = 1.0f / s;
    float4 o0 = {e[0]*inv, e[1]*inv, e[2]*inv, e[3]*inv};
    float4 o1 = {e[4]*inv, e[5]*inv, e[6]*inv, e[7]*inv};
    *(float4*)(p + 4*t) = o0;
    *(float4*)(p + 1024 + 4*t) = o1;
}

// ------- GEMM3: context = align @ value  (single bf16; NT via Vt) ------------
__global__ __launch_bounds__(256)
void lk_gemm_ctx(const float* __restrict__ P, const u16* __restrict__ Vt,
                 float* __restrict__ C)
{
    __shared__ u16 lA[128*ASTR], lB[128*32];
    const int b = blockIdx.z;
    const int m0 = blockIdx.x * 128, n0 = blockIdx.y * 128;
    const int t = threadIdx.x;
    const int w = t >> 6, lane = t & 63, l15 = lane & 15, quad = lane >> 4;

    const float* Pb = P + (size_t)b * TQ * TV;
    const u16* Bb = Vt + (size_t)b * DENC * TV + (size_t)n0 * TV;

    f32x4 acc[2][8];
    #pragma unroll
    for (int i = 0; i < 2; ++i)
        #pragma unroll
        for (int j = 0; j < 8; ++j) acc[i][j] = (f32x4){0.f,0.f,0.f,0.f};

    const int ar = t >> 3, ac = (t & 7) * 4;

    for (int k0 = 0; k0 < TV; k0 += 32) {
        stage_tile(lB, Bb + k0, TV, w, lane);
        #pragma unroll
        for (int it = 0; it < 4; ++it) {
            const int r = ar + it * 32;
            const float4 v = *(const float4*)(Pb + (size_t)(m0 + r) * TV + k0 + ac);
            u16x4 hv = {f2bf(v.x), f2bf(v.y), f2bf(v.z), f2bf(v.w)};
            *(u16x4*)&lA[r*ASTR+ac] = hv;
        }
        __syncthreads();
        bf16x8 af[2];
        #pragma unroll
        for (int tm = 0; tm < 2; ++tm) {
            const int row = w*32 + tm*16 + l15;
            af[tm] = __builtin_bit_cast(bf16x8, *(const u16x8*)&lA[row*ASTR + quad*8]);
        }
        #pragma unroll
        for (int tn = 0; tn < 8; ++tn) {
            const int col = tn*16 + l15;
            const bf16x8 bf = __builtin_bit_cast(bf16x8, *(const u16x8*)&lB[col*32 + quad*8]);
            #pragma unroll
            for (int tm = 0; tm < 2; ++tm)
                acc[tm][tn] = __builtin_amdgcn_mfma_f32_16x16x32_bf16(af[tm], bf, acc[tm][tn], 0,0,0);
        }
        __syncthreads();
    }
    float* Cb = C + (size_t)b * TQ * CTXW;
    #pragma unroll
    for (int tm = 0; tm < 2; ++tm)
        #pragma unroll
        for (int tn = 0; tn < 8; ++tn) {
            const int col = n0 + tn*16 + l15;
            #pragma unroll
            for (int r = 0; r < 4; ++r) {
                const int row = m0 + w*32 + tm*16 + quad*4 + r;
                Cb[(size_t)row*CTXW + col] = acc[tm][tn][r];
            }
        }
}

// ---------------- copy query into ctx cols [DENC, DENC+DDEC) -----------------
__global__ __launch_bounds__(256)
void lk_copy_q(const float* __restrict__ Q, float* __restrict__ C)
{
    const size_t idx = (size_t)blockIdx.x * 256 + threadIdx.x;   // float4 index
    const int d4 = (int)(idx & 255);       // DDEC/4 = 256
    const size_t row = idx >> 8;           // b*TQ + q
    const float4 v = *(const float4*)(Q + (row << 10) + 4*d4);
    *(float4*)(C + row * CTXW + DENC + 4*d4) = v;
}

// ---------------- in-place square transpose per batch: [TQ,TV] --------------
__global__ __launch_bounds__(256)
void lk_transpose(float* __restrict__ A)
{
    const int i = blockIdx.x, j = blockIdx.y;
    if (j < i) return;
    float* Ab = A + (size_t)blockIdx.z * TQ * TV;
    __shared__ float ta[32][36], tb[32][36];
    const int t = threadIdx.x;
    const int r = t >> 3, c = (t & 7) * 4;
    float* pij = Ab + (size_t)(i*32) * TV + j*32;
    float* pji = Ab + (size_t)(j*32) * TV + i*32;
    const float4 va = *(const float4*)(pij + (size_t)r * TV + c);
    *(float4*)&ta[r][c] = va;
    if (i != j) {
        const float4 vb = *(const float4*)(pji + (size_t)r * TV + c);
        *(float4*)&tb[r][c] = vb;
    }
    __syncthreads();
    float4 oa = { ta[c+0][r], ta[c+1][r], ta[c+2][r], ta[c+3][r] };
    *(float4*)(pji + (size_t)r * TV + c) = oa;
    if (i != j) {
        float4 ob = { tb[c+0][r], tb[c+1][r], tb[c+2][r], tb[c+3][r] };
        *(float4*)(pij + (size_t)r * TV + c) = ob;
    }
}

extern "C" void kernel_launch(void* const* d_in, const int* in_sizes, int n_in,
                              void* d_out, int out_size, void* d_ws, size_t ws_size,
                              hipStream_t stream)
{
    (void)in_sizes; (void)n_in; (void)out_size; (void)ws_size;
    const float* Q = (const float*)d_in[0];
    const float* V = (const float*)d_in[1];
    const float* W = (const float*)d_in[2];
    // d_in[3] = bias: softmax-invariant (adds Q·b, constant over v) -> dropped.
    float* out = (float*)d_out;

    float* ctx   = out;                                   // [NB, TQ, CTXW]
    float* align = out + (size_t)NB * TQ * CTXW;          // [NB, TQ, TV]

    // Scores operands staged in the (dead-until-gemm_ctx) ctx region:
    // Q'h/Q'l [NB,TQ,DENC] + Vh/Vl [NB,TV,DENC] = 134 MB < 201 MB.
    u16* q2h = (u16*)ctx;
    u16* q2l = q2h + (size_t)NB * TQ * DENC;
    u16* vsh = q2l + (size_t)NB * TQ * DENC;
    u16* vsl = vsh + (size_t)NB * TV * DENC;

    // ws: Wh/Wl (2.1 MB) + Vt bf16 [NB,DENC,TV] (33.6 MB)
    u16* wh = (u16*)d_ws;
    u16* wl = wh + (size_t)DENC * DDEC;
    u16* vt = wl + (size_t)DENC * DDEC;

    lk_prep_w<<<DENC*DDEC/1024, 256, 0, stream>>>(W, wh, wl);
    lk_prep_v<<<dim3(DENC/32, TV/32, NB), 256, 0, stream>>>(V, vsh, vsl, vt);
    lk_gemm_qw<<<dim3(NB*TQ/128, DENC/128), 256, 0, stream>>>(Q, wh, wl, q2h, q2l);
    lk_gemm_scores<<<dim3(TQ/128, TV/128, NB), 256, 0, stream>>>(q2h, q2l, vsh, vsl, align);
    lk_softmax<<<NB*TQ, 256, 0, stream>>>(align);
    lk_gemm_ctx<<<dim3(TQ/128, DENC/128, NB), 256, 0, stream>>>(align, vt, ctx);
    lk_copy_q<<<NB*TQ*DDEC/1024, 256, 0, stream>>>(Q, ctx);
    lk_transpose<<<dim3(TV/32, TV/32, NB), 256, 0, stream>>>(align);
}